// Round 5
// baseline (187.705 us; speedup 1.0000x reference)
//
#include <hip/hip_runtime.h>

typedef short bf16x8 __attribute__((ext_vector_type(8)));
typedef float f32x4 __attribute__((ext_vector_type(4)));
typedef float f32x16 __attribute__((ext_vector_type(16)));

#define MFMA16(a,b,c) __builtin_amdgcn_mfma_f32_16x16x32_bf16((a),(b),(c),0,0,0)
#define MFMA32(a,b,c) __builtin_amdgcn_mfma_f32_32x32x16_bf16((a),(b),(c),0,0,0)

static __device__ __forceinline__ unsigned short f2bf(float f){
  unsigned u; __builtin_memcpy(&u, &f, 4);
  u += 0x7fffu + ((u >> 16) & 1u);
  return (unsigned short)(u >> 16);
}

// v_cvt_pk_bf16_f32: D = {lo: bf16(lo), hi: bf16(hi)}  (no builtin on gfx950)
static __device__ __forceinline__ unsigned cvtpk(float lo, float hi){
  unsigned r;
  asm volatile("v_cvt_pk_bf16_f32 %0, %1, %2" : "=v"(r) : "v"(lo), "v"(hi));
  return r;
}
// v_permlane32_swap_b32 a, b:  a[l<32]=b_old[l+32]; b[l>=32]=a_old[l-32]
static __device__ __forceinline__ void pl32swap(unsigned &a, unsigned &b){
  asm volatile("v_permlane32_swap_b32 %0, %1" : "+v"(a), "+v"(b));
}

// async global->LDS DMA, 16 B per lane; LDS dest = wave-uniform base + lane*16
static __device__ __forceinline__ void gload_lds16(const void* g, void* l) {
  __builtin_amdgcn_global_load_lds(
      (__attribute__((address_space(1))) void*)g,
      (__attribute__((address_space(3))) void*)l, 16, 0, 0);
}

// ---------------------------------------------------------------------------
// Stage f32 tensor -> bf16.
// ---------------------------------------------------------------------------
__global__ __launch_bounds__(256) void cvt_bf16(
    const float* __restrict__ in, unsigned short* __restrict__ out, int n) {
  int i = blockIdx.x * 256 + threadIdx.x;
  if (i < n) out[i] = f2bf(in[i]);
}

// ---------------------------------------------------------------------------
// T0: x [n][512 c][1024 p] f32 -> xT [n][1024 p][512 c] bf16
// ---------------------------------------------------------------------------
__global__ __launch_bounds__(256) void transpose_cvt(
    const float* __restrict__ in, unsigned short* __restrict__ out)
{
  __shared__ unsigned short tile[32][33];
  const long base = (long)blockIdx.z * 512 * 1024;
  const int t = threadIdx.x, tx = t & 31, ty = t >> 5;
  const int c0 = blockIdx.x * 32, r0 = blockIdx.y * 32;
  const float* ib = in + base;
#pragma unroll
  for (int i = 0; i < 4; ++i)
    tile[ty + i * 8][tx] = f2bf(ib[(long)(r0 + ty + i * 8) * 1024 + c0 + tx]);
  __syncthreads();
  unsigned short* ob = out + base;
#pragma unroll
  for (int i = 0; i < 4; ++i)
    ob[(long)(c0 + ty + i * 8) * 512 + r0 + tx] = tile[tx][ty + i * 8];
}

// ---------------------------------------------------------------------------
// K1: QKV GEMM. Double-buffered LDS, stage(next) before compute(cur), one
// barrier per K-step. XCD-grouped remap (each XCD = 2 batches). q/k epilogue
// transposes through LDS for 16B-contiguous stores.
// ---------------------------------------------------------------------------
__global__ __launch_bounds__(256, 2) void gemm_qkv(
    const unsigned short* __restrict__ A, const unsigned short* __restrict__ B,
    unsigned short* __restrict__ qkvout, const float* __restrict__ bias)
{
  const int M = 1024, K = 512;
  __shared__ unsigned short SM[4][128 * 64];   // A0 A1 B0 B1, 64 KB
  const int t = threadIdx.x, lane = t & 63, wv = t >> 6;
  const int quad = lane >> 4, ln = lane & 15;

  // bijective XCD remap: L in [0,1536), v = (L%8)*192 + L/8
  const int L = blockIdx.x + 12 * blockIdx.y + 96 * blockIdx.z;
  const int v = (L & 7) * 192 + (L >> 3);
  const int m0 = ((v / 12) & 7) * 128, n0 = (v % 12) * 128;
  const long zb = v / 96;
  A += zb * (long)M * K;

  const int srow = wv * 32 + (lane >> 3);
  const int scol = ((lane & 7) * 8) ^ ((lane >> 3) * 8);

  auto stage = [&](int kt, unsigned short* Ad, unsigned short* Bd) {
#pragma unroll
    for (int i = 0; i < 4; ++i) {
      gload_lds16(&A[(long)(m0 + srow + i * 8) * K + kt + scol],
                  &Ad[(wv * 32 + i * 8) * 64]);
      gload_lds16(&B[(long)(n0 + srow + i * 8) * K + kt + scol],
                  &Bd[(wv * 32 + i * 8) * 64]);
    }
  };

  f32x4 zero = {0.f, 0.f, 0.f, 0.f};
  f32x4 acc[4][4];
#pragma unroll
  for (int i = 0; i < 4; ++i)
#pragma unroll
    for (int j = 0; j < 4; ++j) acc[i][j] = zero;

  const int wm = (wv & 1) * 64, wn = (wv >> 1) * 64;
  const int rsw = (ln & 7) * 8;

  stage(0, SM[0], SM[2]);
  __syncthreads();
  for (int kt8 = 0; kt8 < 8; ++kt8) {
    const int cur = kt8 & 1;
    if (kt8 < 7) stage((kt8 + 1) * 64, SM[cur ^ 1], SM[2 + (cur ^ 1)]);
    const unsigned short* As = SM[cur];
    const unsigned short* Bs = SM[2 + cur];
#pragma unroll
    for (int kk = 0; kk < 64; kk += 32) {
      bf16x8 a[4], b[4];
#pragma unroll
      for (int i = 0; i < 4; ++i)
        a[i] = *(const bf16x8*)&As[(wm + i * 16 + ln) * 64 + ((kk + quad * 8) ^ rsw)];
#pragma unroll
      for (int j = 0; j < 4; ++j)
        b[j] = *(const bf16x8*)&Bs[(wn + j * 16 + ln) * 64 + ((kk + quad * 8) ^ rsw)];
#pragma unroll
      for (int i = 0; i < 4; ++i)
#pragma unroll
        for (int j = 0; j < 4; ++j)
          acc[i][j] = MFMA16(a[i], b[j], acc[i][j]);
    }
    __syncthreads();   // prefetch landed + all waves done with cur buffers
  }

  const int part = n0 >> 9;   // uniform per block: 0=q, 1=k, 2=v
  if (part < 2) {
    // ---- transpose epilogue through LDS: T[p][o'] bf16, padded row 136 ----
    const float qs = (part == 0) ? 0.18033688f : 1.0f;  // 0.125 * log2(e)
    unsigned short (*T)[136] = (unsigned short(*)[136])&SM[0][0];  // 34 KB
#pragma unroll
    for (int j = 0; j < 4; ++j) {
      const int oo = wn + j * 16 + ln;
      const float bb = bias[n0 + oo];
#pragma unroll
      for (int i = 0; i < 4; ++i) {
        const int pp = wm + i * 16 + quad * 4;
        f32x4 vv = acc[i][j];
#pragma unroll
        for (int r = 0; r < 4; ++r)
          T[pp + r][oo] = f2bf((vv[r] + bb) * qs);
      }
    }
    __syncthreads();
    unsigned short* qb = qkvout + (long)part * 8388608;
#pragma unroll
    for (int it = 0; it < 8; ++it) {
      const int idx = it * 256 + t;
      const int p = idx >> 4, c0 = (idx & 15) * 8;
      const int og = n0 + c0;
      const int h = (og >> 6) & 7, d = og & 63;
      bf16x8 val = *(const bf16x8*)&T[p][c0];
      *(bf16x8*)&qb[((long)(zb * 8 + h) * 1024 + m0 + p) * 64 + d] = val;
    }
  } else {
    // ---- v part: [c][p] layout, stores already p-contiguous ----
#pragma unroll
    for (int j = 0; j < 4; ++j) {
      const int o = n0 + wn + j * 16 + ln;
      const float bb = bias[o];
#pragma unroll
      for (int i = 0; i < 4; ++i) {
        const int p = m0 + wm + i * 16 + quad * 4;
        const long cidx = ((long)zb * 512 + (o - 1024)) * 1024 + p;
        f32x4 vv = acc[i][j];
        ushort4 st;
        st.x = f2bf(vv[0] + bb); st.y = f2bf(vv[1] + bb);
        st.z = f2bf(vv[2] + bb); st.w = f2bf(vv[3] + bb);
        *(ushort4*)&qkvout[16777216 + cidx] = st;
      }
    }
  }
}

// ---------------------------------------------------------------------------
// K3: OUT GEMM, same pipeline + XCD remap; bias+dropout+residual.
// ---------------------------------------------------------------------------
__global__ __launch_bounds__(256, 2) void gemm_out(
    const unsigned short* __restrict__ A, const unsigned short* __restrict__ B,
    float* __restrict__ C, const float* __restrict__ bias,
    const float* __restrict__ xin, const int* __restrict__ de_ptr)
{
  const int M = 1024, K = 512;
  __shared__ unsigned short SM[4][128 * 64];   // A0 A1 B0 B1, 64 KB
  const int t = threadIdx.x, lane = t & 63, wv = t >> 6;
  const int quad = lane >> 4, ln = lane & 15;

  // bijective XCD remap: L in [0,512), v = (L%8)*64 + L/8
  const int L = blockIdx.x + 4 * blockIdx.y + 32 * blockIdx.z;
  const int v = (L & 7) * 64 + (L >> 3);
  const int m0 = ((v >> 2) & 7) * 128, n0 = (v & 3) * 128;
  const long zb = v >> 5;
  A += zb * (long)M * K;
  C += zb * 512l * M;
  xin += zb * 512l * M;

  const int srow = wv * 32 + (lane >> 3);
  const int scol = ((lane & 7) * 8) ^ ((lane >> 3) * 8);

  auto stage = [&](int kt, unsigned short* Ad, unsigned short* Bd) {
#pragma unroll
    for (int i = 0; i < 4; ++i) {
      gload_lds16(&A[(long)(m0 + srow + i * 8) * K + kt + scol],
                  &Ad[(wv * 32 + i * 8) * 64]);
      gload_lds16(&B[(long)(n0 + srow + i * 8) * K + kt + scol],
                  &Bd[(wv * 32 + i * 8) * 64]);
    }
  };

  f32x4 zero = {0.f, 0.f, 0.f, 0.f};
  f32x4 acc[4][4];
#pragma unroll
  for (int i = 0; i < 4; ++i)
#pragma unroll
    for (int j = 0; j < 4; ++j) acc[i][j] = zero;

  const int wm = (wv & 1) * 64, wn = (wv >> 1) * 64;
  const int rsw = (ln & 7) * 8;

  stage(0, SM[0], SM[2]);
  __syncthreads();
  for (int kt8 = 0; kt8 < 8; ++kt8) {
    const int cur = kt8 & 1;
    if (kt8 < 7) stage((kt8 + 1) * 64, SM[cur ^ 1], SM[2 + (cur ^ 1)]);
    const unsigned short* As = SM[cur];
    const unsigned short* Bs = SM[2 + cur];
#pragma unroll
    for (int kk = 0; kk < 64; kk += 32) {
      bf16x8 a[4], b[4];
#pragma unroll
      for (int i = 0; i < 4; ++i)
        a[i] = *(const bf16x8*)&As[(wm + i * 16 + ln) * 64 + ((kk + quad * 8) ^ rsw)];
#pragma unroll
      for (int j = 0; j < 4; ++j)
        b[j] = *(const bf16x8*)&Bs[(wn + j * 16 + ln) * 64 + ((kk + quad * 8) ^ rsw)];
#pragma unroll
      for (int i = 0; i < 4; ++i)
#pragma unroll
        for (int j = 0; j < 4; ++j)
          acc[i][j] = MFMA16(a[i], b[j], acc[i][j]);
    }
    __syncthreads();
  }

  float dscale = 1.0f / (1.0f - 0.1f * (float)de_ptr[0]);

#pragma unroll
  for (int j = 0; j < 4; ++j) {
    int o = n0 + wn + j * 16 + ln;
    float bb = bias[o];
#pragma unroll
    for (int i = 0; i < 4; ++i) {
      int p = m0 + wm + i * 16 + quad * 4;
      long cidx = (long)o * M + p;
      f32x4 vv = acc[i][j];
      float4 rx = *(const float4*)&xin[cidx];
      float4 st;
      st.x = rx.x + (vv[0] + bb) * dscale;
      st.y = rx.y + (vv[1] + bb) * dscale;
      st.z = rx.z + (vv[2] + bb) * dscale;
      st.w = rx.w + (vv[3] + bb) * dscale;
      *(float4*)&C[cidx] = st;
    }
  }
}

// ---------------------------------------------------------------------------
// Flash attention v9: 8 waves x 32 q (was 4 waves x 64 q). Same 512 blocks,
// same 64 KB LDS (2 blocks/CU), but 4 waves/SIMD instead of 2 -> double the
// latency hiding; per-wave dependence chain halves. 32x32x16 MFMA,
// in-register P via cvt_pk+permlane32_swap, double-buffered K/V DMA,
// XCD-grouping swizzle, setprio around MFMA clusters.
// ---------------------------------------------------------------------------
__global__ __launch_bounds__(512, 4) void attn_kernel(
    const unsigned short* __restrict__ q_pd, const unsigned short* __restrict__ k_pd,
    const unsigned short* __restrict__ v_cp, unsigned short* __restrict__ y_pc)
{
  __shared__ unsigned short Ks[2][128 * 64];     // 2 x 16 KB, DMA dest
  __shared__ unsigned short Vs[2][64 * 128];     // 2 x 16 KB, DMA dest
  const int t = threadIdx.x, lane = t & 63, wv = t >> 6;   // wv 0..7
  const int l31 = lane & 31, bh8 = (lane >> 5) * 8;
  const int qt = blockIdx.y >> 5;                     // 0..3 q-tile
  const int nh = blockIdx.x * 32 + (blockIdx.y & 31); // 0..127
  const int n = nh >> 3, h = nh & 7;
  const int q0 = qt * 256;

  // Q fragments (B-operand, 32x32x16): n=q=l31, k=d=ds*16+bh8+j. Pre-scaled.
  bf16x8 qa[4];
  {
    const unsigned short* qb =
        q_pd + ((long)nh * 1024 + q0 + wv * 32 + l31) * 64;
#pragma unroll
    for (int ds = 0; ds < 4; ++ds)
      qa[ds] = *(const bf16x8*)(qb + ds * 16 + bh8);
  }

  f32x16 zacc;
#pragma unroll
  for (int r = 0; r < 16; ++r) zacc[r] = 0.f;
  f32x16 o_acc[2];
  o_acc[0] = zacc; o_acc[1] = zacc;
  float l_acc = 0.f;

  const unsigned short* kg0 = k_pd + (long)nh * 1024 * 64;
  const unsigned short* vg0 = v_cp + ((long)n * 512 + h * 64) * 1024;

  // staging coords: 8 waves. K: 2 issues x 8 rows (wave rows [wv*16,+16));
  // V: 2 issues x 4 rows (wave rows [wv*8,+8)). Source cols inverse-swizzled.
  const int krow = lane >> 3;
  const int kcol = ((lane & 7) * 8) ^ ((lane >> 3) * 8);
  const int vrow = lane >> 4;
  const int rsw = (lane & 7) * 8;     // K read XOR (frag row&7 == lane&7)
  const int vrsw = (l31 & 15) * 8;    // V read XOR (frag row&15 == l31&15)

  auto stage_kv = [&](const unsigned short* kg, const unsigned short* vg,
                      unsigned short* KsD, unsigned short* VsD) {
#pragma unroll
    for (int i = 0; i < 2; ++i) {
      const int vr = ((wv & 1) * 8) + i * 4 + vrow;       // V row & 15
      const int vcol = ((lane & 15) ^ vr) * 8;
      gload_lds16(kg + (long)(wv * 16 + i * 8 + krow) * 64 + kcol,
                  &KsD[(wv * 16 + i * 8) * 64]);
      gload_lds16(vg + (long)(wv * 8 + i * 4 + vrow) * 1024 + vcol,
                  &VsD[(wv * 8 + i * 4) * 128]);
    }
  };

  // prologue: stage chunk 0 into buffer 0
  stage_kv(kg0, vg0, Ks[0], Vs[0]);
  __syncthreads();

  union U { bf16x8 v; unsigned u[4]; };
  auto sm_pack = [&](const f32x16& sv, bf16x8* paq) {
    float e[16];
#pragma unroll
    for (int r = 0; r < 16; ++r) e[r] = __builtin_amdgcn_exp2f(sv[r]);
    float ls = 0.f;
#pragma unroll
    for (int r = 0; r < 16; ++r) ls += e[r];
    l_acc += ls;
    unsigned pk4[4][2];
#pragma unroll
    for (int hh = 0; hh < 4; ++hh) {
      pk4[hh][0] = cvtpk(e[4 * hh + 0], e[4 * hh + 1]);
      pk4[hh][1] = cvtpk(e[4 * hh + 2], e[4 * hh + 3]);
    }
#pragma unroll
    for (int hk = 0; hk < 2; ++hk) {
      unsigned a0 = pk4[2 * hk + 1][0], b0 = pk4[2 * hk][0];
      unsigned a1 = pk4[2 * hk + 1][1], b1 = pk4[2 * hk][1];
      pl32swap(a0, b0); pl32swap(a1, b1);
      U u; u.u[0] = b0; u.u[1] = b1; u.u[2] = a0; u.u[3] = a1;
      paq[hk] = u.v;
    }
  };

  for (int c = 0; c < 8; ++c) {
    const int cur = c & 1;
    if (c < 7)
      stage_kv(kg0 + (long)(c + 1) * 128 * 64, vg0 + (c + 1) * 128,
               Ks[cur ^ 1], Vs[cur ^ 1]);
    const unsigned short* KsC = Ks[cur];
    const unsigned short* VsC = Vs[cur];

#pragma unroll
    for (int kgi = 0; kgi < 4; ++kgi) {
      // ---- S^T = K Q^T over 32-key group kgi ----
      f32x16 s = zacc;
      __builtin_amdgcn_s_setprio(1);
#pragma unroll
      for (int ds = 0; ds < 4; ++ds) {
        bf16x8 ka = *(const bf16x8*)&KsC[(kgi * 32 + l31) * 64 + ((ds * 16 + bh8) ^ rsw)];
        s = MFMA32(ka, qa[ds], s);
      }
      __builtin_amdgcn_s_setprio(0);
      // ---- softmax partial + in-register P^T B-frags ----
      bf16x8 pa[2];
      sm_pack(s, pa);
      // ---- O^T += V^T P^T for this key group ----
      __builtin_amdgcn_s_setprio(1);
#pragma unroll
      for (int dg = 0; dg < 2; ++dg)
#pragma unroll
        for (int hk = 0; hk < 2; ++hk) {
          bf16x8 va = *(const bf16x8*)
              &VsC[(dg * 32 + l31) * 128 + (((kgi * 2 + hk) * 16 + bh8) ^ vrsw)];
          o_acc[dg] = MFMA32(va, pa[hk], o_acc[dg]);
        }
      __builtin_amdgcn_s_setprio(0);
    }
    __syncthreads();   // staged DMA landed + all waves done with cur buffers
  }

  // ---- epilogue: normalize, store y_pc [n][p=q][c = h*64 + d] ----
  {
    float la = l_acc;
    la += __shfl_xor(la, 32);
    float linv = 1.0f / la;
    const int q = q0 + wv * 32 + l31;
    unsigned short* yb = y_pc + ((long)n * 1024 + q) * 512 + h * 64;
#pragma unroll
    for (int dg = 0; dg < 2; ++dg) {
      f32x16 o = o_acc[dg];
#pragma unroll
      for (int rq = 0; rq < 4; ++rq) {
        int d0 = dg * 32 + rq * 8 + (bh8 >> 1);   // (lane>>5)*4
        ushort4 st;
        st.x = f2bf(o[rq * 4 + 0] * linv);
        st.y = f2bf(o[rq * 4 + 1] * linv);
        st.z = f2bf(o[rq * 4 + 2] * linv);
        st.w = f2bf(o[rq * 4 + 3] * linv);
        *(ushort4*)&yb[d0] = st;
      }
    }
  }
}

// ---------------------------------------------------------------------------
extern "C" void kernel_launch(void* const* d_in, const int* in_sizes, int n_in,
                              void* d_out, int out_size, void* d_ws, size_t ws_size,
                              hipStream_t stream) {
  (void)in_sizes; (void)n_in; (void)out_size; (void)ws_size;
  const float* x     = (const float*)d_in[0];
  const float* qkv_w = (const float*)d_in[1];
  const float* qkv_b = (const float*)d_in[2];
  const float* out_w = (const float*)d_in[3];
  const float* out_b = (const float*)d_in[4];
  const int* de = (const int*)d_in[5];
  float* out = (float*)d_out;
  unsigned short* ws = (unsigned short*)d_ws;

  // ws layout (shorts), ~66 MiB total:
  //   [0, 8388608)            xT, reused as y_pc
  //   [8388608, 33554432)     qkv: q_pd | k_pd | v_cp (8388608 each)
  //   [33554432, 34340864)    wq bf16 (786432)
  //   [34340864, 34603008)    wo bf16 (262144)
  unsigned short* xT   = ws;
  unsigned short* qkv  = ws + 8388608;
  unsigned short* y_pc = ws;
  unsigned short* wq   = ws + 33554432;
  unsigned short* wo   = wq + 786432;

  cvt_bf16<<<3072, 256, 0, stream>>>(qkv_w, wq, 786432);
  cvt_bf16<<<1024, 256, 0, stream>>>(out_w, wo, 262144);

  transpose_cvt<<<dim3(32, 16, 16), 256, 0, stream>>>(x, xT);

  gemm_qkv<<<dim3(12, 8, 16), 256, 0, stream>>>(xT, wq, qkv, qkv_b);

  attn_kernel<<<dim3(4, 128), 512, 0, stream>>>(
      qkv, qkv + 8388608, qkv + 16777216, y_pc);

  gemm_out<<<dim3(4, 8, 16), 256, 0, stream>>>(
      y_pc, wo, out, out_b, x, de);
}